// Round 1
// baseline (1623.938 us; speedup 1.0000x reference)
//
#include <hip/hip_runtime.h>
#include <math.h>

#define SIZE_N   (1 << 25)       // 33554432
#define FLATD    30000000
#define FLATD4   7500000         // FLATD / 4 (exact)
#define LOW_N    8192            // 2^13 low-bit FWHT tile
#define HIGH_N   4096            // 2^12 high-bit rows
#define NCOL4    2048            // SIZE_N/4 per row... (float4 row stride = 8192/4 * ... see usage)

// ---------------- K1: pad(theta)*B fused with low-13-bit FWHT ----------------
__global__ __launch_bounds__(256) void k1_padB_fwht_low(const float* __restrict__ theta,
                                                        const float* __restrict__ B,
                                                        float* __restrict__ x) {
    __shared__ float lds[LOW_N];
    float4* lds4 = (float4*)lds;
    const int t   = threadIdx.x;
    const int blk = blockIdx.x;              // 4096 blocks
    const int base4 = blk * (LOW_N / 4);     // float4 index base
    const float4* B4  = (const float4*)B;
    const float4* th4 = (const float4*)theta;

#pragma unroll
    for (int i = 0; i < 8; ++i) {
        int l4 = t + (i << 8);
        int g4 = base4 + l4;
        float4 b = B4[g4];
        float4 v = make_float4(0.f, 0.f, 0.f, 0.f);
        if (g4 < FLATD4) v = th4[g4];
        v.x *= b.x; v.y *= b.y; v.z *= b.z; v.w *= b.w;
        lds4[l4] = v;
    }

    for (int s = 0; s < 13; ++s) {
        __syncthreads();
        int h = 1 << s;
#pragma unroll
        for (int i = 0; i < 16; ++i) {
            int p   = t + (i << 8);                       // pair id 0..4095
            int idx = ((p >> s) << (s + 1)) | (p & (h - 1));
            float a = lds[idx];
            float b2 = lds[idx + h];
            lds[idx]     = a + b2;
            lds[idx + h] = a - b2;
        }
    }
    __syncthreads();

    float4* x4 = (float4*)x;
#pragma unroll
    for (int i = 0; i < 8; ++i) {
        int l4 = t + (i << 8);
        x4[base4 + l4] = lds4[l4];
    }
}

// ---------------- K2: high-12-bit FWHT in place on x ----------------
// view x as [4096 rows][8192 cols]; FWHT over rows. Tile = all rows x 4 cols.
__global__ __launch_bounds__(256) void k2_fwht_high(float* __restrict__ x) {
    __shared__ float lds[HIGH_N * 4];        // 64 KB: lds[r*4 + c]
    float4* lds4 = (float4*)lds;
    const int t   = threadIdx.x;
    const int blk = blockIdx.x;              // 2048 blocks, cols 4*blk..4*blk+3
    float4* x4 = (float4*)x;

#pragma unroll
    for (int i = 0; i < 16; ++i) {
        int r = t + (i << 8);                // row 0..4095
        lds4[r] = x4[r * 2048 + blk];        // float4 index = (r*8192 + blk*4)/4
    }

    for (int s = 0; s < 12; ++s) {
        __syncthreads();
        int h = 1 << s;
#pragma unroll
        for (int i = 0; i < 32; ++i) {
            int w = t + (i << 8);            // work item 0..8191
            int c = w & 3;
            int p = w >> 2;                  // pair id 0..2047
            int r = ((p >> s) << (s + 1)) | (p & (h - 1));
            int a0 = (r << 2) | c;
            int a1 = ((r + h) << 2) | c;
            float a = lds[a0];
            float b = lds[a1];
            lds[a0] = a + b;
            lds[a1] = a - b;
        }
    }
    __syncthreads();

#pragma unroll
    for (int i = 0; i < 16; ++i) {
        int r = t + (i << 8);
        x4[r * 2048 + blk] = lds4[r];
    }
}

// ---------------- K3: y = x[Pi]*G fused with low-13-bit FWHT ----------------
__global__ __launch_bounds__(256) void k3_gather_fwht_low(const float* __restrict__ x,
                                                          const int* __restrict__ Pi,
                                                          const float* __restrict__ G,
                                                          float* __restrict__ y) {
    __shared__ float lds[LOW_N];
    float4* lds4 = (float4*)lds;
    const int t   = threadIdx.x;
    const int blk = blockIdx.x;              // 4096 blocks
    const int base4 = blk * (LOW_N / 4);
    const int4*   Pi4 = (const int4*)Pi;
    const float4* G4  = (const float4*)G;

#pragma unroll
    for (int i = 0; i < 8; ++i) {
        int l4 = t + (i << 8);
        int g4 = base4 + l4;
        int4   p4 = Pi4[g4];
        float4 g  = G4[g4];
        float4 v;
        v.x = x[p4.x] * g.x;
        v.y = x[p4.y] * g.y;
        v.z = x[p4.z] * g.z;
        v.w = x[p4.w] * g.w;
        lds4[l4] = v;
    }

    for (int s = 0; s < 13; ++s) {
        __syncthreads();
        int h = 1 << s;
#pragma unroll
        for (int i = 0; i < 16; ++i) {
            int p   = t + (i << 8);
            int idx = ((p >> s) << (s + 1)) | (p & (h - 1));
            float a = lds[idx];
            float b2 = lds[idx + h];
            lds[idx]     = a + b2;
            lds[idx + h] = a - b2;
        }
    }
    __syncthreads();

    float4* y4 = (float4*)y;
#pragma unroll
    for (int i = 0; i < 8; ++i) {
        int l4 = t + (i << 8);
        y4[base4 + l4] = lds4[l4];
    }
}

// ---------------- K4: high-12-bit FWHT on y fused with truncate + scale ----------------
__global__ __launch_bounds__(256) void k4_fwht_high_out(const float* __restrict__ y,
                                                        const float* __restrict__ divisor,
                                                        float* __restrict__ out) {
    __shared__ float lds[HIGH_N * 4];
    float4* lds4 = (float4*)lds;
    const int t   = threadIdx.x;
    const int blk = blockIdx.x;              // 2048 blocks
    const float4* y4 = (const float4*)y;

#pragma unroll
    for (int i = 0; i < 16; ++i) {
        int r = t + (i << 8);
        lds4[r] = y4[r * 2048 + blk];
    }

    const float scale = divisor[0] * sqrtf((float)FLATD / (float)SIZE_N);
    const float inv   = 1.0f / scale;

    for (int s = 0; s < 12; ++s) {
        __syncthreads();
        int h = 1 << s;
#pragma unroll
        for (int i = 0; i < 32; ++i) {
            int w = t + (i << 8);
            int c = w & 3;
            int p = w >> 2;
            int r = ((p >> s) << (s + 1)) | (p & (h - 1));
            int a0 = (r << 2) | c;
            int a1 = ((r + h) << 2) | c;
            float a = lds[a0];
            float b = lds[a1];
            lds[a0] = a + b;
            lds[a1] = a - b;
        }
    }
    __syncthreads();

    float4* out4 = (float4*)out;
#pragma unroll
    for (int i = 0; i < 16; ++i) {
        int r  = t + (i << 8);
        int o4 = r * 2048 + blk;             // float4 index in element space
        if (o4 < FLATD4) {
            float4 v = lds4[r];
            v.x *= inv; v.y *= inv; v.z *= inv; v.w *= inv;
            out4[o4] = v;
        }
    }
}

extern "C" void kernel_launch(void* const* d_in, const int* in_sizes, int n_in,
                              void* d_out, int out_size, void* d_ws, size_t ws_size,
                              hipStream_t stream) {
    const float* theta   = (const float*)d_in[0];
    const float* G       = (const float*)d_in[1];
    const float* B       = (const float*)d_in[2];
    const float* divisor = (const float*)d_in[3];
    const int*   Pi      = (const int*)d_in[4];
    float* out = (float*)d_out;

    float* x = (float*)d_ws;                 // SIZE_N floats (134 MB)
    float* y = x + SIZE_N;                   // SIZE_N floats (134 MB)

    k1_padB_fwht_low<<<SIZE_N / LOW_N, 256, 0, stream>>>(theta, B, x);
    k2_fwht_high<<<LOW_N / 4, 256, 0, stream>>>(x);
    k3_gather_fwht_low<<<SIZE_N / LOW_N, 256, 0, stream>>>(x, Pi, G, y);
    k4_fwht_high_out<<<LOW_N / 4, 256, 0, stream>>>(y, divisor, out);
}